// Round 1
// baseline (494.616 us; speedup 1.0000x reference)
//
#include <hip/hip_runtime.h>
#include <hip/hip_bf16.h>
#include <stdint.h>

// Problem constants (fixed by setup_inputs)
#define NE   8
#define DOUT 2048
#define DIN  2048
#define SEQ  8192
#define GSZ  128
#define FP8_MAX 448.0f
#define EPSQ 1e-12f

typedef float f32x4 __attribute__((ext_vector_type(4)));

// ---------------------------------------------------------------------------
// async global->LDS copy, 16B per lane. LDS dest must be wave-uniform base;
// HW adds lane*16.
__device__ __forceinline__ void async16(void* lds_base, const void* gptr) {
    __builtin_amdgcn_global_load_lds(
        (const __attribute__((address_space(1))) unsigned int*)gptr,
        (__attribute__((address_space(3))) unsigned int*)lds_base,
        16, 0, 0);
}

// ---------------------------------------------------------------------------
// Kernel 1: per-1x128-tile quant of x. One wave per tile, 4 waves/block.
__global__ __launch_bounds__(256) void quant_x_kernel(
    const float* __restrict__ x, unsigned char* __restrict__ qx,
    float* __restrict__ sx)
{
    const int tile = blockIdx.x * 4 + (threadIdx.x >> 6);
    const int lane = threadIdx.x & 63;
    const int row = tile >> 4;        // 0..8191
    const int tb  = tile & 15;        // k-block 0..15

    const float2 v = *(const float2*)(x + (size_t)row * DIN + tb * GSZ + lane * 2);
    float a = fmaxf(fabsf(v.x), fabsf(v.y));
    #pragma unroll
    for (int o = 32; o; o >>= 1) a = fmaxf(a, __shfl_xor(a, o));
    const float scale = fmaxf(a, EPSQ) / FP8_MAX;
    if (lane == 0) sx[row * 16 + tb] = scale;

    float q0 = fminf(fmaxf(v.x / scale, -FP8_MAX), FP8_MAX);
    float q1 = fminf(fmaxf(v.y / scale, -FP8_MAX), FP8_MAX);
    int p = __builtin_amdgcn_cvt_pk_fp8_f32(q0, q1, 0, false);
    *(unsigned short*)(qx + (size_t)row * DIN + tb * GSZ + lane * 2) =
        (unsigned short)(p & 0xffff);
}

// ---------------------------------------------------------------------------
// Kernel 2: per-128x128-block quant of w. One 256-thread block per block.
__global__ __launch_bounds__(256) void quant_w_kernel(
    const float* __restrict__ w, unsigned char* __restrict__ qw,
    float* __restrict__ sw)
{
    const int cb = blockIdx.x;   // din block 0..15
    const int rb = blockIdx.y;   // dout block 0..15
    const int e  = blockIdx.z;   // expert 0..7
    const int t  = threadIdx.x;
    const int lane = t & 63, wv = t >> 6;

    const size_t base = ((size_t)e * DOUT + rb * GSZ) * DIN + cb * GSZ;
    const float* wp = w + base;

    float4 v[16];
    float a = 0.f;
    #pragma unroll
    for (int i = 0; i < 16; ++i) {
        int idx = t + i * 256;         // 0..4095
        int r = idx >> 5, c4 = idx & 31;
        v[i] = *(const float4*)(wp + (size_t)r * DIN + c4 * 4);
        a = fmaxf(a, fmaxf(fmaxf(fabsf(v[i].x), fabsf(v[i].y)),
                           fmaxf(fabsf(v[i].z), fabsf(v[i].w))));
    }
    #pragma unroll
    for (int o = 32; o; o >>= 1) a = fmaxf(a, __shfl_xor(a, o));
    __shared__ float red[4];
    if (lane == 0) red[wv] = a;
    __syncthreads();
    a = fmaxf(fmaxf(red[0], red[1]), fmaxf(red[2], red[3]));
    const float scale = fmaxf(a, EPSQ) / FP8_MAX;
    if (t == 0) sw[(e * 16 + rb) * 16 + cb] = scale;

    unsigned int* qout = (unsigned int*)(qw + base);
    #pragma unroll
    for (int i = 0; i < 16; ++i) {
        int idx = t + i * 256;
        int r = idx >> 5, c4 = idx & 31;
        float q0 = fminf(fmaxf(v[i].x / scale, -FP8_MAX), FP8_MAX);
        float q1 = fminf(fmaxf(v[i].y / scale, -FP8_MAX), FP8_MAX);
        float q2 = fminf(fmaxf(v[i].z / scale, -FP8_MAX), FP8_MAX);
        float q3 = fminf(fmaxf(v[i].w / scale, -FP8_MAX), FP8_MAX);
        int lo = __builtin_amdgcn_cvt_pk_fp8_f32(q0, q1, 0, false);
        int pk = __builtin_amdgcn_cvt_pk_fp8_f32(q2, q3, lo, true);
        qout[r * (DIN / 4) + c4] = (unsigned int)pk;
    }
}

// ---------------------------------------------------------------------------
// Kernel 3: grouped fp8 GEMM with per-k-block scaling.
// out[s,n] = sum_kb sx[s,kb]*sw[e,n/128,kb] * sum_{k in kb} qx[s,k]*qw[e,n,k]
// Tiles: BM=BN=BK=128. 256 threads = 4 waves in 2x2, each wave 64x64
// (4x4 MFMA tiles of 16x16x32 fp8).
__global__ __launch_bounds__(256, 2) void gemm_kernel(
    const unsigned char* __restrict__ qx, const float* __restrict__ sx,
    const unsigned char* __restrict__ qw, const float* __restrict__ sw,
    const int* __restrict__ tpe, float* __restrict__ out)
{
    __shared__ unsigned char Asm[128 * 128];
    __shared__ unsigned char Bsm[128 * 128];
    __shared__ float sxT[16 * 128];   // [kb][row]

    const int tid  = threadIdx.x;
    const int lane = tid & 63;
    const int wv   = tid >> 6;
    const int wm   = wv >> 1, wn = wv & 1;
    const int quad = lane >> 4;
    const int l16  = lane & 15;
    const int nb   = blockIdx.x;      // 0..15
    const int mb   = blockIdx.y;      // 0..63
    const int r0   = mb * 128, n0 = nb * 128;

    // expert for this row tile (boundaries are 128-aligned in this problem)
    int e = -1, start = 0;
    #pragma unroll
    for (int i = 0; i < NE; ++i) {
        int end = start + tpe[i];
        if (r0 >= start && r0 < end) e = i;
        start = end;
    }
    if (e < 0) {   // rows owned by no expert -> zeros
        f32x4 z = {0.f, 0.f, 0.f, 0.f};
        for (int i = tid; i < 128 * 32; i += 256) {
            int r = i >> 5, c4 = i & 31;
            *(f32x4*)(out + (size_t)(r0 + r) * DOUT + n0 + c4 * 4) = z;
        }
        return;
    }

    // preload sx tile transposed: sxT[kb][r] = sx[r0+r][kb]
    {
        const float* sp = sx + (size_t)r0 * 16;
        for (int i = tid; i < 2048; i += 256) {
            int r = i >> 4, kb = i & 15;
            sxT[kb * 128 + r] = sp[i];
        }
    }

    const unsigned char* Ag = qx + (size_t)r0 * DIN;
    const unsigned char* Bg = qw + (size_t)e * DOUT * DIN + (size_t)n0 * DIN;
    const float* swp = sw + (e * 16 + nb) * 16;

    f32x4 acc[4][4];
    f32x4 zero4 = {0.f, 0.f, 0.f, 0.f};
    #pragma unroll
    for (int mi = 0; mi < 4; ++mi)
        #pragma unroll
        for (int ni = 0; ni < 4; ++ni) acc[mi][ni] = zero4;

    for (int kb = 0; kb < 16; ++kb) {
        __syncthreads();   // prev-iter LDS reads done before overwrite
        // stage A and B tiles (16 KB each) via global_load_lds width=16
        #pragma unroll
        for (int j = 0; j < 4; ++j) {
            int f = wv * 4096 + j * 1024 + lane * 16;
            int row = f >> 7, cbyte = f & 127;
            async16(Asm + wv * 4096 + j * 1024,
                    Ag + (size_t)row * DIN + kb * GSZ + cbyte);
            async16(Bsm + wv * 4096 + j * 1024,
                    Bg + (size_t)row * DIN + kb * GSZ + cbyte);
        }
        __syncthreads();   // drains vmcnt before barrier

        const float swv = swp[kb];

        // cache all B fragments for this k-block: [kstep][ni]
        long bf[4][4];
        #pragma unroll
        for (int ks = 0; ks < 4; ++ks)
            #pragma unroll
            for (int ni = 0; ni < 4; ++ni) {
                int nrow = wn * 64 + ni * 16 + l16;
                bf[ks][ni] = *(const long*)(Bsm + nrow * 128 + ks * 32 + quad * 8);
            }

        #pragma unroll
        for (int mi = 0; mi < 4; ++mi) {
            int mrow = wm * 64 + mi * 16 + l16;
            long af[4];
            #pragma unroll
            for (int ks = 0; ks < 4; ++ks)
                af[ks] = *(const long*)(Asm + mrow * 128 + ks * 32 + quad * 8);

            f32x4 ak[4];
            #pragma unroll
            for (int ni = 0; ni < 4; ++ni) ak[ni] = zero4;
            #pragma unroll
            for (int ks = 0; ks < 4; ++ks)
                #pragma unroll
                for (int ni = 0; ni < 4; ++ni)
                    ak[ni] = __builtin_amdgcn_mfma_f32_16x16x32_fp8_fp8(
                        af[ks], bf[ks][ni], ak[ni], 0, 0, 0);

            // combined scale for this k-block; row = quad*4 + reg
            const f32x4 sv = *(const f32x4*)(sxT + kb * 128 + wm * 64 + mi * 16 + quad * 4);
            float s0 = sv[0] * swv, s1 = sv[1] * swv,
                  s2 = sv[2] * swv, s3 = sv[3] * swv;
            #pragma unroll
            for (int ni = 0; ni < 4; ++ni) {
                acc[mi][ni][0] += ak[ni][0] * s0;
                acc[mi][ni][1] += ak[ni][1] * s1;
                acc[mi][ni][2] += ak[ni][2] * s2;
                acc[mi][ni][3] += ak[ni][3] * s3;
            }
        }
    }

    // epilogue: C/D layout col=lane&15, row=quad*4+reg
    #pragma unroll
    for (int mi = 0; mi < 4; ++mi) {
        int rbase = r0 + wm * 64 + mi * 16 + quad * 4;
        #pragma unroll
        for (int ni = 0; ni < 4; ++ni) {
            int col = n0 + wn * 64 + ni * 16 + l16;
            #pragma unroll
            for (int r = 0; r < 4; ++r)
                out[(size_t)(rbase + r) * DOUT + col] = acc[mi][ni][r];
        }
    }
}

// ---------------------------------------------------------------------------
extern "C" void kernel_launch(void* const* d_in, const int* in_sizes, int n_in,
                              void* d_out, int out_size, void* d_ws, size_t ws_size,
                              hipStream_t stream) {
    const float* x   = (const float*)d_in[0];   // [8192, 2048] fp32
    const float* wt  = (const float*)d_in[1];   // [16384, 2048] fp32
    const int*   tpe = (const int*)d_in[2];     // [8]
    float* out = (float*)d_out;                 // [8192, 2048] fp32

    char* ws = (char*)d_ws;
    unsigned char* qx = (unsigned char*)ws;                       // 16 MB
    unsigned char* qw = qx + (size_t)SEQ * DIN;                   // 32 MB
    float* sx = (float*)(qw + (size_t)NE * DOUT * DIN);           // 512 KB
    float* sw = sx + (size_t)SEQ * 16;                            // 4 KB

    quant_x_kernel<<<SEQ * 16 / 4, 256, 0, stream>>>(x, qx, sx);
    quant_w_kernel<<<dim3(16, 16, NE), 256, 0, stream>>>(wt, qw, sw);
    gemm_kernel<<<dim3(DOUT / 128, SEQ / 128), 256, 0, stream>>>(
        qx, sx, qw, sw, tpe, out);
}

// Round 3
// 320.395 us; speedup vs baseline: 1.5438x; 1.5438x over previous
//
#include <hip/hip_runtime.h>
#include <hip/hip_bf16.h>
#include <stdint.h>

// Problem constants (fixed by setup_inputs)
#define NE   8
#define DOUT 2048
#define DIN  2048
#define SEQ  8192
#define GSZ  128
#define FP8_MAX 448.0f
#define EPSQ 1e-12f

typedef float f32x4 __attribute__((ext_vector_type(4)));

// async global->LDS, 16B/lane. LDS dest = wave-uniform base (+lane*16 by HW);
// global src may be per-lane.
__device__ __forceinline__ void async16(void* lds_base, const void* gptr) {
    __builtin_amdgcn_global_load_lds(
        (const __attribute__((address_space(1))) unsigned int*)gptr,
        (__attribute__((address_space(3))) unsigned int*)lds_base,
        16, 0, 0);
}

// ---------------------------------------------------------------------------
// Kernel 1: per-1x128-tile quant of x. One float4 per thread; each 32-lane
// half-wave group covers one tile. Coalesced float4 loads, dword stores.
__global__ __launch_bounds__(256) void quant_x_kernel(
    const float* __restrict__ x, unsigned char* __restrict__ qx,
    float* __restrict__ sx)
{
    const int g = blockIdx.x * 256 + threadIdx.x;   // float4 group index
    const float4 v = ((const float4*)x)[g];
    float a = fmaxf(fmaxf(fabsf(v.x), fabsf(v.y)),
                    fmaxf(fabsf(v.z), fabsf(v.w)));
    #pragma unroll
    for (int o = 16; o; o >>= 1) a = fmaxf(a, __shfl_xor(a, o));  // 32-lane tile
    const float scale = fmaxf(a, EPSQ) / FP8_MAX;
    const int tile = g >> 5;                        // == row*16 + kb
    if ((threadIdx.x & 31) == 0) sx[tile] = scale;

    float q0 = fminf(fmaxf(v.x / scale, -FP8_MAX), FP8_MAX);
    float q1 = fminf(fmaxf(v.y / scale, -FP8_MAX), FP8_MAX);
    float q2 = fminf(fmaxf(v.z / scale, -FP8_MAX), FP8_MAX);
    float q3 = fminf(fmaxf(v.w / scale, -FP8_MAX), FP8_MAX);
    int lo = __builtin_amdgcn_cvt_pk_fp8_f32(q0, q1, 0, false);
    int pk = __builtin_amdgcn_cvt_pk_fp8_f32(q2, q3, lo, true);
    ((unsigned int*)qx)[g] = (unsigned int)pk;
}

// ---------------------------------------------------------------------------
// Kernel 2: per-128x128-block quant of w. Stage block into 64 KB LDS via
// global_load_lds, amax from LDS, quantize from LDS. No register hoard.
// NOTE: a block row is 512 B = 32 sixteen-byte chunks (R2 bug: used 8 -> OOB).
__global__ __launch_bounds__(256) void quant_w_kernel(
    const float* __restrict__ w, unsigned char* __restrict__ qw,
    float* __restrict__ sw)
{
    __shared__ float buf[128 * 128];   // 64 KB
    __shared__ float red[4];

    const int cb = blockIdx.x;   // din block 0..15
    const int rb = blockIdx.y;   // dout block 0..15
    const int e  = blockIdx.z;   // expert 0..7
    const int t  = threadIdx.x;
    const int lane = t & 63, wv = t >> 6;

    const size_t base = ((size_t)e * DOUT + rb * GSZ) * DIN + cb * GSZ;
    const float* wp = w + base;

    // stage 64 KB: 4 waves x 16 iters x 1 KB. LDS layout = row-major block.
    #pragma unroll
    for (int j = 0; j < 16; ++j) {
        int f16 = (wv * 16 + j) * 64 + lane;     // 16-byte chunk index 0..4095
        int row = f16 >> 5, cc = f16 & 31;       // 32 chunks per 512B row
        async16(buf + (wv * 16 + j) * 256,
                wp + (size_t)row * DIN + cc * 4);
    }
    __syncthreads();

    // amax over the block
    float a = 0.f;
    #pragma unroll
    for (int i = 0; i < 16; ++i) {
        f32x4 v = *(const f32x4*)(buf + (t + i * 256) * 4);
        a = fmaxf(a, fmaxf(fmaxf(fabsf(v[0]), fabsf(v[1])),
                           fmaxf(fabsf(v[2]), fabsf(v[3]))));
    }
    #pragma unroll
    for (int o = 32; o; o >>= 1) a = fmaxf(a, __shfl_xor(a, o));
    if (lane == 0) red[wv] = a;
    __syncthreads();
    a = fmaxf(fmaxf(red[0], red[1]), fmaxf(red[2], red[3]));
    const float scale = fmaxf(a, EPSQ) / FP8_MAX;
    if (t == 0) sw[(e * 16 + rb) * 16 + cb] = scale;

    unsigned int* qout = (unsigned int*)(qw + base);
    #pragma unroll
    for (int i = 0; i < 16; ++i) {
        int idx = t + i * 256;                   // float4 slot in block
        f32x4 v = *(const f32x4*)(buf + idx * 4);
        float q0 = fminf(fmaxf(v[0] / scale, -FP8_MAX), FP8_MAX);
        float q1 = fminf(fmaxf(v[1] / scale, -FP8_MAX), FP8_MAX);
        float q2 = fminf(fmaxf(v[2] / scale, -FP8_MAX), FP8_MAX);
        float q3 = fminf(fmaxf(v[3] / scale, -FP8_MAX), FP8_MAX);
        int lo = __builtin_amdgcn_cvt_pk_fp8_f32(q0, q1, 0, false);
        int pk = __builtin_amdgcn_cvt_pk_fp8_f32(q2, q3, lo, true);
        int r = idx >> 5, c4 = idx & 31;
        qout[r * (DIN / 4) + c4] = (unsigned int)pk;
    }
}

// ---------------------------------------------------------------------------
// Kernel 3: grouped fp8 GEMM with per-k-block scaling.
// LDS tiles are XOR-swizzled: the 16B chunk at logical (row, lc) is stored at
// physical chunk pc = lc ^ (row & 7). Staging fetches the swizzled global
// source per lane; fragment reads hit all 32 banks uniformly (4/bank, the
// b64 minimum) instead of the previous 16-way conflict.
__global__ __launch_bounds__(256, 3) void gemm_kernel(
    const unsigned char* __restrict__ qx, const float* __restrict__ sx,
    const unsigned char* __restrict__ qw, const float* __restrict__ sw,
    const int* __restrict__ tpe, float* __restrict__ out)
{
    __shared__ unsigned char Asm[128 * 128];
    __shared__ unsigned char Bsm[128 * 128];
    __shared__ float sxT[16 * 128];   // [kb][row]

    const int tid  = threadIdx.x;
    const int lane = tid & 63;
    const int wv   = tid >> 6;
    const int wm   = wv >> 1, wn = wv & 1;
    const int quad = lane >> 4;
    const int l16  = lane & 15;
    const int nb   = blockIdx.x;      // 0..15
    const int mb   = blockIdx.y;      // 0..63
    const int r0   = mb * 128, n0 = nb * 128;

    int e = -1, start = 0;
    #pragma unroll
    for (int i = 0; i < NE; ++i) {
        int end = start + tpe[i];
        if (r0 >= start && r0 < end) e = i;
        start = end;
    }
    if (e < 0) {
        f32x4 z = {0.f, 0.f, 0.f, 0.f};
        for (int i = tid; i < 128 * 32; i += 256) {
            int r = i >> 5, c4 = i & 31;
            *(f32x4*)(out + (size_t)(r0 + r) * DOUT + n0 + c4 * 4) = z;
        }
        return;
    }

    {   // sxT[kb][r] = sx[r0+r][kb]
        const float* sp = sx + (size_t)r0 * 16;
        for (int i = tid; i < 2048; i += 256) {
            int r = i >> 4, kb = i & 15;
            sxT[kb * 128 + r] = sp[i];
        }
    }

    const unsigned char* Ag = qx + (size_t)r0 * DIN;
    const unsigned char* Bg = qw + (size_t)e * DOUT * DIN + (size_t)n0 * DIN;
    const float* swp = sw + (e * 16 + nb) * 16;

    // staging source indices (per-lane, loop-invariant): physical chunk ->
    // swizzled logical chunk
    int srow[4], scol[4];
    #pragma unroll
    for (int j = 0; j < 4; ++j) {
        int f = wv * 4096 + j * 1024 + lane * 16;
        int row = f >> 7, pc = (f >> 4) & 7;
        srow[j] = row;
        scol[j] = (pc ^ (row & 7)) * 16;
    }

    // fragment read offsets (physical, swizzled)
    int aoff[4][4];   // [mi][ks]
    int boff[4][4];   // [ni][ks]
    #pragma unroll
    for (int i = 0; i < 4; ++i)
        #pragma unroll
        for (int ks = 0; ks < 4; ++ks) {
            int lc = ks * 2 + (quad >> 1), wd = (quad & 1) * 8;
            int mrow = wm * 64 + i * 16 + l16;
            aoff[i][ks] = mrow * 128 + ((lc ^ (mrow & 7)) * 16) + wd;
            int nrow = wn * 64 + i * 16 + l16;
            boff[i][ks] = nrow * 128 + ((lc ^ (nrow & 7)) * 16) + wd;
        }

    f32x4 acc[4][4];
    f32x4 zero4 = {0.f, 0.f, 0.f, 0.f};
    #pragma unroll
    for (int mi = 0; mi < 4; ++mi)
        #pragma unroll
        for (int ni = 0; ni < 4; ++ni) acc[mi][ni] = zero4;

    for (int kb = 0; kb < 16; ++kb) {
        __syncthreads();
        #pragma unroll
        for (int j = 0; j < 4; ++j) {
            async16(Asm + wv * 4096 + j * 1024,
                    Ag + (size_t)srow[j] * DIN + kb * GSZ + scol[j]);
            async16(Bsm + wv * 4096 + j * 1024,
                    Bg + (size_t)srow[j] * DIN + kb * GSZ + scol[j]);
        }
        __syncthreads();

        const float swv = swp[kb];

        long bf[4][4];
        #pragma unroll
        for (int ks = 0; ks < 4; ++ks)
            #pragma unroll
            for (int ni = 0; ni < 4; ++ni)
                bf[ks][ni] = *(const long*)(Bsm + boff[ni][ks]);

        #pragma unroll
        for (int mi = 0; mi < 4; ++mi) {
            long af[4];
            #pragma unroll
            for (int ks = 0; ks < 4; ++ks)
                af[ks] = *(const long*)(Asm + aoff[mi][ks]);

            f32x4 ak[4];
            #pragma unroll
            for (int ni = 0; ni < 4; ++ni) ak[ni] = zero4;
            #pragma unroll
            for (int ks = 0; ks < 4; ++ks)
                #pragma unroll
                for (int ni = 0; ni < 4; ++ni)
                    ak[ni] = __builtin_amdgcn_mfma_f32_16x16x32_fp8_fp8(
                        af[ks], bf[ks][ni], ak[ni], 0, 0, 0);

            const f32x4 sv = *(const f32x4*)(sxT + kb * 128 + wm * 64 + mi * 16 + quad * 4);
            float s0 = sv[0] * swv, s1 = sv[1] * swv,
                  s2 = sv[2] * swv, s3 = sv[3] * swv;
            #pragma unroll
            for (int ni = 0; ni < 4; ++ni) {
                acc[mi][ni][0] += ak[ni][0] * s0;
                acc[mi][ni][1] += ak[ni][1] * s1;
                acc[mi][ni][2] += ak[ni][2] * s2;
                acc[mi][ni][3] += ak[ni][3] * s3;
            }
        }
    }

    // epilogue: C/D layout col=lane&15, row=quad*4+reg
    #pragma unroll
    for (int mi = 0; mi < 4; ++mi) {
        int rbase = r0 + wm * 64 + mi * 16 + quad * 4;
        #pragma unroll
        for (int ni = 0; ni < 4; ++ni) {
            int col = n0 + wn * 64 + ni * 16 + l16;
            #pragma unroll
            for (int r = 0; r < 4; ++r)
                out[(size_t)(rbase + r) * DOUT + col] = acc[mi][ni][r];
        }
    }
}

// ---------------------------------------------------------------------------
extern "C" void kernel_launch(void* const* d_in, const int* in_sizes, int n_in,
                              void* d_out, int out_size, void* d_ws, size_t ws_size,
                              hipStream_t stream) {
    const float* x   = (const float*)d_in[0];   // [8192, 2048] fp32
    const float* wt  = (const float*)d_in[1];   // [16384, 2048] fp32
    const int*   tpe = (const int*)d_in[2];     // [8]
    float* out = (float*)d_out;                 // [8192, 2048] fp32

    char* ws = (char*)d_ws;
    unsigned char* qx = (unsigned char*)ws;                       // 16 MB
    unsigned char* qw = qx + (size_t)SEQ * DIN;                   // 32 MB
    float* sx = (float*)(qw + (size_t)NE * DOUT * DIN);           // 512 KB
    float* sw = sx + (size_t)SEQ * 16;                            // 4 KB

    quant_x_kernel<<<SEQ * DIN / 4 / 256, 256, 0, stream>>>(x, qx, sx);
    quant_w_kernel<<<dim3(16, 16, NE), 256, 0, stream>>>(wt, qw, sw);
    gemm_kernel<<<dim3(DOUT / 128, SEQ / 128), 256, 0, stream>>>(
        qx, sx, qw, sw, tpe, out);
}

// Round 4
// 302.090 us; speedup vs baseline: 1.6373x; 1.0606x over previous
//
#include <hip/hip_runtime.h>
#include <hip/hip_bf16.h>
#include <stdint.h>

// Problem constants (fixed by setup_inputs)
#define NE   8
#define DOUT 2048
#define DIN  2048
#define SEQ  8192
#define GSZ  128
#define FP8_MAX 448.0f
#define EPSQ 1e-12f

typedef float f32x4 __attribute__((ext_vector_type(4)));

// async global->LDS, 16B/lane. LDS dest = wave-uniform base (+lane*16 by HW);
// global src may be per-lane.
__device__ __forceinline__ void async16(void* lds_base, const void* gptr) {
    __builtin_amdgcn_global_load_lds(
        (const __attribute__((address_space(1))) unsigned int*)gptr,
        (__attribute__((address_space(3))) unsigned int*)lds_base,
        16, 0, 0);
}

// ---------------------------------------------------------------------------
// Kernel 1: per-1x128-tile quant of x. One float4 per thread; each 32-lane
// half-wave group covers one tile. Coalesced float4 loads, dword stores.
__global__ __launch_bounds__(256) void quant_x_kernel(
    const float* __restrict__ x, unsigned char* __restrict__ qx,
    float* __restrict__ sx)
{
    const int g = blockIdx.x * 256 + threadIdx.x;   // float4 group index
    const float4 v = ((const float4*)x)[g];
    float a = fmaxf(fmaxf(fabsf(v.x), fabsf(v.y)),
                    fmaxf(fabsf(v.z), fabsf(v.w)));
    #pragma unroll
    for (int o = 16; o; o >>= 1) a = fmaxf(a, __shfl_xor(a, o));  // 32-lane tile
    const float scale = fmaxf(a, EPSQ) / FP8_MAX;
    const int tile = g >> 5;                        // == row*16 + kb
    if ((threadIdx.x & 31) == 0) sx[tile] = scale;

    float q0 = fminf(fmaxf(v.x / scale, -FP8_MAX), FP8_MAX);
    float q1 = fminf(fmaxf(v.y / scale, -FP8_MAX), FP8_MAX);
    float q2 = fminf(fmaxf(v.z / scale, -FP8_MAX), FP8_MAX);
    float q3 = fminf(fmaxf(v.w / scale, -FP8_MAX), FP8_MAX);
    int lo = __builtin_amdgcn_cvt_pk_fp8_f32(q0, q1, 0, false);
    int pk = __builtin_amdgcn_cvt_pk_fp8_f32(q2, q3, lo, true);
    ((unsigned int*)qx)[g] = (unsigned int)pk;
}

// ---------------------------------------------------------------------------
// Kernel 2: per-128x128-block quant of w. Stage block into 64 KB LDS via
// global_load_lds, amax from LDS, quantize from LDS.
__global__ __launch_bounds__(256) void quant_w_kernel(
    const float* __restrict__ w, unsigned char* __restrict__ qw,
    float* __restrict__ sw)
{
    __shared__ float buf[128 * 128];   // 64 KB
    __shared__ float red[4];

    const int cb = blockIdx.x;   // din block 0..15
    const int rb = blockIdx.y;   // dout block 0..15
    const int e  = blockIdx.z;   // expert 0..7
    const int t  = threadIdx.x;
    const int lane = t & 63, wv = t >> 6;

    const size_t base = ((size_t)e * DOUT + rb * GSZ) * DIN + cb * GSZ;
    const float* wp = w + base;

    // stage 64 KB: 4 waves x 16 iters x 1 KB. 32 sixteen-byte chunks per row.
    #pragma unroll
    for (int j = 0; j < 16; ++j) {
        int f16 = (wv * 16 + j) * 64 + lane;     // 16-byte chunk index 0..4095
        int row = f16 >> 5, cc = f16 & 31;
        async16(buf + (wv * 16 + j) * 256,
                wp + (size_t)row * DIN + cc * 4);
    }
    __syncthreads();

    float a = 0.f;
    #pragma unroll
    for (int i = 0; i < 16; ++i) {
        f32x4 v = *(const f32x4*)(buf + (t + i * 256) * 4);
        a = fmaxf(a, fmaxf(fmaxf(fabsf(v[0]), fabsf(v[1])),
                           fmaxf(fabsf(v[2]), fabsf(v[3]))));
    }
    #pragma unroll
    for (int o = 32; o; o >>= 1) a = fmaxf(a, __shfl_xor(a, o));
    if (lane == 0) red[wv] = a;
    __syncthreads();
    a = fmaxf(fmaxf(red[0], red[1]), fmaxf(red[2], red[3]));
    const float scale = fmaxf(a, EPSQ) / FP8_MAX;
    if (t == 0) sw[(e * 16 + rb) * 16 + cb] = scale;

    unsigned int* qout = (unsigned int*)(qw + base);
    #pragma unroll
    for (int i = 0; i < 16; ++i) {
        int idx = t + i * 256;
        f32x4 v = *(const f32x4*)(buf + idx * 4);
        float q0 = fminf(fmaxf(v[0] / scale, -FP8_MAX), FP8_MAX);
        float q1 = fminf(fmaxf(v[1] / scale, -FP8_MAX), FP8_MAX);
        float q2 = fminf(fmaxf(v[2] / scale, -FP8_MAX), FP8_MAX);
        float q3 = fminf(fmaxf(v[3] / scale, -FP8_MAX), FP8_MAX);
        int lo = __builtin_amdgcn_cvt_pk_fp8_f32(q0, q1, 0, false);
        int pk = __builtin_amdgcn_cvt_pk_fp8_f32(q2, q3, lo, true);
        int r = idx >> 5, c4 = idx & 31;
        qout[r * (DIN / 4) + c4] = (unsigned int)pk;
    }
}

// ---------------------------------------------------------------------------
// Kernel 3: grouped fp8 GEMM, in-place MFMA accumulation with telescoped
// per-k-block rescaling:
//   out[s,n] = c[s,15]*A15,  A_j = A_{j-1}*r_j + P_j,  r_j = c[s,j-1]/c[s,j],
//   c[s,j] = sx[s,j]*sw[e,nb,j]  (one scale per 128-k block per 128-col block)
// Rs[kb][row] holds r_kb for kb>=1; Rs[0][row] holds the final scale c[·,15].
// LDS tiles XOR-swizzled (chunk pc = lc ^ (row&7)) to kill bank conflicts.
// LDS total = 32 KB tiles + 8 KB Rs = 40 KB -> 4 blocks/CU; grid 1024 = 256*4.
__global__ __launch_bounds__(256, 4) void gemm_kernel(
    const unsigned char* __restrict__ qx, const float* __restrict__ sx,
    const unsigned char* __restrict__ qw, const float* __restrict__ sw,
    const int* __restrict__ tpe, float* __restrict__ out)
{
    __shared__ unsigned char Asm[128 * 128];
    __shared__ unsigned char Bsm[128 * 128];
    __shared__ float Rs[16 * 128];   // [kb][row]

    const int tid  = threadIdx.x;
    const int lane = tid & 63;
    const int wv   = tid >> 6;
    const int wm   = wv >> 1, wn = wv & 1;
    const int quad = lane >> 4;
    const int l16  = lane & 15;
    const int nb   = blockIdx.x;      // 0..15
    const int mb   = blockIdx.y;      // 0..63
    const int r0   = mb * 128, n0 = nb * 128;

    int e = -1, start = 0;
    #pragma unroll
    for (int i = 0; i < NE; ++i) {
        int end = start + tpe[i];
        if (r0 >= start && r0 < end) e = i;
        start = end;
    }
    if (e < 0) {
        f32x4 z = {0.f, 0.f, 0.f, 0.f};
        for (int i = tid; i < 128 * 32; i += 256) {
            int r = i >> 5, c4 = i & 31;
            *(f32x4*)(out + (size_t)(r0 + r) * DOUT + n0 + c4 * 4) = z;
        }
        return;
    }

    // ---- prologue: c = sx*sw into Asm scratch, then ratios into Rs ----
    {
        float* Cs = (float*)Asm;              // 8 KB scratch inside A tile
        const float* sp  = sx + (size_t)r0 * 16;
        const float* swp = sw + (e * 16 + nb) * 16;
        for (int i = tid; i < 2048; i += 256) {
            int r = i >> 4, kb = i & 15;
            Cs[kb * 128 + r] = sp[i] * swp[kb];
        }
        __syncthreads();
        float rv[8];
        #pragma unroll
        for (int j = 0; j < 8; ++j) {
            int i = tid + j * 256;
            int kb = i >> 7, row = i & 127;
            rv[j] = (kb == 0) ? Cs[15 * 128 + row]
                              : Cs[(kb - 1) * 128 + row] / Cs[kb * 128 + row];
        }
        #pragma unroll
        for (int j = 0; j < 8; ++j) Rs[tid + j * 256] = rv[j];
        // loop-top __syncthreads() orders: Cs reads done before Asm staging,
        // Rs writes visible before first rescale use (kb=1).
    }

    const unsigned char* Ag = qx + (size_t)r0 * DIN;
    const unsigned char* Bg = qw + (size_t)e * DOUT * DIN + (size_t)n0 * DIN;

    // staging source indices (per-lane, loop-invariant)
    int srow[4], scol[4];
    #pragma unroll
    for (int j = 0; j < 4; ++j) {
        int f = wv * 4096 + j * 1024 + lane * 16;
        int row = f >> 7, pc = (f >> 4) & 7;
        srow[j] = row;
        scol[j] = (pc ^ (row & 7)) * 16;
    }

    // fragment read offsets: off(ks) = base + 32*(ks ^ xr), where
    // base = row*128 + (quad&1)*8 + 16*((quad>>1) ^ (row&1)), xr = (row&7)>>1
    int abase[4], axr[4], bbase[4], bxr[4];
    const int q2h = quad >> 1, wd = (quad & 1) * 8;
    #pragma unroll
    for (int i = 0; i < 4; ++i) {
        int mrow = wm * 64 + i * 16 + l16;
        abase[i] = mrow * 128 + wd + 16 * (q2h ^ (mrow & 1));
        axr[i]   = (mrow & 7) >> 1;
        int nrow = wn * 64 + i * 16 + l16;
        bbase[i] = nrow * 128 + wd + 16 * (q2h ^ (nrow & 1));
        bxr[i]   = (nrow & 7) >> 1;
    }

    f32x4 acc[4][4];
    f32x4 zero4 = {0.f, 0.f, 0.f, 0.f};
    #pragma unroll
    for (int mi = 0; mi < 4; ++mi)
        #pragma unroll
        for (int ni = 0; ni < 4; ++ni) acc[mi][ni] = zero4;

    for (int kb = 0; kb < 16; ++kb) {
        __syncthreads();
        #pragma unroll
        for (int j = 0; j < 4; ++j) {
            async16(Asm + wv * 4096 + j * 1024,
                    Ag + (size_t)srow[j] * DIN + kb * GSZ + scol[j]);
            async16(Bsm + wv * 4096 + j * 1024,
                    Bg + (size_t)srow[j] * DIN + kb * GSZ + scol[j]);
        }
        __syncthreads();

        if (kb) {   // rescale accumulators into this k-block's units
            #pragma unroll
            for (int mi = 0; mi < 4; ++mi) {
                const f32x4 rr = *(const f32x4*)(Rs + kb * 128 + wm * 64 + mi * 16 + quad * 4);
                #pragma unroll
                for (int ni = 0; ni < 4; ++ni) {
                    acc[mi][ni][0] *= rr[0];
                    acc[mi][ni][1] *= rr[1];
                    acc[mi][ni][2] *= rr[2];
                    acc[mi][ni][3] *= rr[3];
                }
            }
        }

        #pragma unroll
        for (int ks = 0; ks < 4; ++ks) {
            long af[4], bf[4];
            #pragma unroll
            for (int i = 0; i < 4; ++i) {
                af[i] = *(const long*)(Asm + abase[i] + 32 * (ks ^ axr[i]));
                bf[i] = *(const long*)(Bsm + bbase[i] + 32 * (ks ^ bxr[i]));
            }
            #pragma unroll
            for (int mi = 0; mi < 4; ++mi)
                #pragma unroll
                for (int ni = 0; ni < 4; ++ni)
                    acc[mi][ni] = __builtin_amdgcn_mfma_f32_16x16x32_fp8_fp8(
                        af[mi], bf[ni], acc[mi][ni], 0, 0, 0);
        }
    }

    // epilogue: apply final scale (Rs kb=0 slot). C/D: col=l16, row=quad*4+r
    #pragma unroll
    for (int mi = 0; mi < 4; ++mi) {
        const f32x4 fv = *(const f32x4*)(Rs + wm * 64 + mi * 16 + quad * 4);
        int rbase = r0 + wm * 64 + mi * 16 + quad * 4;
        #pragma unroll
        for (int ni = 0; ni < 4; ++ni) {
            int col = n0 + wn * 64 + ni * 16 + l16;
            #pragma unroll
            for (int r = 0; r < 4; ++r)
                out[(size_t)(rbase + r) * DOUT + col] = acc[mi][ni][r] * fv[r];
        }
    }
}

// ---------------------------------------------------------------------------
extern "C" void kernel_launch(void* const* d_in, const int* in_sizes, int n_in,
                              void* d_out, int out_size, void* d_ws, size_t ws_size,
                              hipStream_t stream) {
    const float* x   = (const float*)d_in[0];   // [8192, 2048] fp32
    const float* wt  = (const float*)d_in[1];   // [16384, 2048] fp32
    const int*   tpe = (const int*)d_in[2];     // [8]
    float* out = (float*)d_out;                 // [8192, 2048] fp32

    char* ws = (char*)d_ws;
    unsigned char* qx = (unsigned char*)ws;                       // 16 MB
    unsigned char* qw = qx + (size_t)SEQ * DIN;                   // 32 MB
    float* sx = (float*)(qw + (size_t)NE * DOUT * DIN);           // 512 KB
    float* sw = sx + (size_t)SEQ * 16;                            // 4 KB

    quant_x_kernel<<<SEQ * DIN / 4 / 256, 256, 0, stream>>>(x, qx, sx);
    quant_w_kernel<<<dim3(16, 16, NE), 256, 0, stream>>>(wt, qw, sw);
    gemm_kernel<<<dim3(DOUT / 128, SEQ / 128), 256, 0, stream>>>(
        qx, sx, qw, sw, tpe, out);
}